// Round 21
// baseline (205.913 us; speedup 1.0000x reference)
//
#include <hip/hip_runtime.h>
#include <stdint.h>

typedef __bf16 bf16x8 __attribute__((ext_vector_type(8)));
typedef float f32x4 __attribute__((ext_vector_type(4)));
typedef unsigned short ushort8 __attribute__((ext_vector_type(8)));
typedef unsigned short ushort4v __attribute__((ext_vector_type(4)));

constexpr int CB = 4;
constexpr int CL = 2048;
constexpr int CD = 1024;
constexpr int CH = 16;
constexpr int CDH = 64;
constexpr int CM = CB * CL;  // 8192

__device__ __forceinline__ unsigned short f2bf(float f) {
  union { float f; unsigned u; } x; x.f = f;
  unsigned r = x.u + 0x7fffu + ((x.u >> 16) & 1u);
  return (unsigned short)(r >> 16);
}
__device__ __forceinline__ float bf2f(unsigned short b) {
  union { unsigned u; float f; } x; x.u = ((unsigned)b) << 16;
  return x.f;
}

__device__ __forceinline__ void gld_lds16(const void* g, void* l) {
  __builtin_amdgcn_global_load_lds((const __attribute__((address_space(1))) void*)g,
                                   (__attribute__((address_space(3))) void*)l, 16, 0, 0);
}

#define MFMA16(a, b, c) __builtin_amdgcn_mfma_f32_16x16x32_bf16((a), (b), (c), 0, 0, 0)

// ---------------- fp32 -> bf16: weights + q/k/v in ONE launch ------------------

__global__ __launch_bounds__(256) void cvt_all(const float* __restrict__ q,
                                               const float* __restrict__ k,
                                               const float* __restrict__ v,
                                               const float* __restrict__ Wq,
                                               const float* __restrict__ Wk,
                                               const float* __restrict__ Wv,
                                               const float* __restrict__ Wc,
                                               unsigned short* __restrict__ oq,
                                               unsigned short* __restrict__ ok,
                                               unsigned short* __restrict__ ov,
                                               unsigned short* __restrict__ oWq,
                                               unsigned short* __restrict__ oWk,
                                               unsigned short* __restrict__ oWv,
                                               unsigned short* __restrict__ oWc) {
  int bi = blockIdx.x;
  const float* s;
  unsigned short* d;
  int i;
  if (bi < 2048) {
    const int w = bi >> 9;
    i = (bi & 511) * 256 + threadIdx.x;
    s = w == 0 ? Wq : w == 1 ? Wk : w == 2 ? Wv : Wc;
    d = w == 0 ? oWq : w == 1 ? oWk : w == 2 ? oWv : oWc;
  } else {
    bi -= 2048;
    const int w = bi >> 12;
    i = (bi & 4095) * 256 + threadIdx.x;
    s = w == 0 ? q : w == 1 ? k : v;
    d = w == 0 ? oq : w == 1 ? ok : ov;
  }
  const float4* sp = (const float4*)s;
  float4 a = sp[2 * i], b = sp[2 * i + 1];
  ushort8 o;
  o[0] = f2bf(a.x); o[1] = f2bf(a.y); o[2] = f2bf(a.z); o[3] = f2bf(a.w);
  o[4] = f2bf(b.x); o[5] = f2bf(b.y); o[6] = f2bf(b.z); o[7] = f2bf(b.w);
  ((ushort8*)d)[i] = o;
}

// ---------------- lengths from prefix mask ----------------

__global__ __launch_bounds__(256) void lens_kernel(const int* __restrict__ mask,
                                                   int* __restrict__ lens) {
  __shared__ int part[4];
  const int b = blockIdx.x;
  int cnt = 0;
  for (int i = threadIdx.x; i < CL; i += 256) cnt += (mask[b * CL + i] != 0) ? 1 : 0;
#pragma unroll
  for (int off = 32; off; off >>= 1) cnt += __shfl_down(cnt, off);
  if ((threadIdx.x & 63) == 0) part[threadIdx.x >> 6] = cnt;
  __syncthreads();
  if (threadIdx.x == 0) lens[b] = part[0] + part[1] + part[2] + part[3];
}

// ---------------- GEMM core: m97 4-wave 64x64 wave-tile + counted-vmcnt ring ---
// 256 threads, 128x128 tile, BK=32, acc[4][4]/wave: per wave-step 16 MFMA vs
// 8 ds_read_b128 (2:1 compute:LDS, vs 1.33:1 at the old 8-wave shape -> LDS
// pipe no longer the bottleneck). 3-buffer ring (48KB -> 3 blocks/CU), one
// s_barrier + counted vmcnt per step; 4 gld_lds/thread/stage => steady wait
// vmcnt(4). Race-free as R18: stage(t+2) overwrites buf(t-1) after barrier(t).

#define GEMM_WAIT4(kt, nkt)                                             \
  {                                                                     \
    if ((kt) + 1 < (nkt))                                               \
      asm volatile("s_waitcnt vmcnt(4)" ::: "memory");                  \
    else                                                                \
      asm volatile("s_waitcnt vmcnt(0)" ::: "memory");                  \
    __builtin_amdgcn_s_barrier();                                       \
    asm volatile("" ::: "memory");                                      \
  }

// ---------------- fused QKV GEMM (bf16 A via global_load_lds), N = 3072 --------

__global__ __launch_bounds__(256) void gemm_qkv(const unsigned short* __restrict__ Xq,
                                                const unsigned short* __restrict__ Xk,
                                                const unsigned short* __restrict__ Xv,
                                                const unsigned short* __restrict__ Wb,
                                                const float* __restrict__ bq,
                                                const float* __restrict__ bk,
                                                const float* __restrict__ bv,
                                                unsigned short* __restrict__ Qp,
                                                unsigned short* __restrict__ Kp,
                                                unsigned short* __restrict__ Vt,
                                                float qscale) {
  __shared__ unsigned short Asm[3][128 * 32];
  __shared__ unsigned short Bsm[3][128 * 32];
  const int tid = threadIdx.x;
  const int w = tid >> 6, ln = tid & 63, lr = ln & 15, lq = ln >> 4;
  const int nbx = 24;  // 3072/128
  const int cpx = (int)gridDim.x >> 3;
  const int bid = ((int)blockIdx.x & 7) * cpx + ((int)blockIdx.x >> 3);
  const int bm = (bid / nbx) << 7;
  const int bnG = (bid % nbx) << 7;
  const int which = bnG >> 10, bn = bnG & 1023;
  const unsigned short* A = which == 0 ? Xq : which == 1 ? Xk : Xv;
  const unsigned short* Bw = Wb + ((size_t)which << 20);
  const float* bias = which == 0 ? bq : which == 1 ? bk : bv;
  const float alpha = which == 0 ? qscale : 1.0f;
  const int wr = (w >> 1) << 6, wc = (w & 1) << 6;  // wave tile 64x64

  f32x4 acc[4][4] = {};

  auto stage = [&](int buf, int k0) {
#pragma unroll
    for (int p = 0; p < 2; ++p) {
      const int idx = (p << 8) + (w << 6) + ln;      // chunk 0..511
      const int row = idx >> 2, cc = (idx & 3) << 3;
      gld_lds16(A + (size_t)(bm + row) * CD + k0 + cc,
                (void*)(Asm[buf] + (size_t)((p << 8) + (w << 6)) * 8));
      gld_lds16(Bw + (size_t)(bn + row) * CD + k0 + cc,
                (void*)(Bsm[buf] + (size_t)((p << 8) + (w << 6)) * 8));
    }
  };

  stage(0, 0);
  stage(1, 32);

  const int nkt = CD >> 5;  // 32
  int cur = 0;
  for (int kt = 0; kt < nkt; ++kt) {
    GEMM_WAIT4(kt, nkt);
    if (kt + 2 < nkt) {
      int nb = cur + 2;
      if (nb >= 3) nb -= 3;
      stage(nb, (kt + 2) << 5);
    }
    bf16x8 af[4], bfr[4];
#pragma unroll
    for (int f = 0; f < 4; ++f) {
      af[f] = *(const bf16x8*)(Asm[cur] + ((wr + f * 16 + lr) * 32 + lq * 8));
      bfr[f] = *(const bf16x8*)(Bsm[cur] + ((wc + f * 16 + lr) * 32 + lq * 8));
    }
#pragma unroll
    for (int fm = 0; fm < 4; ++fm)
#pragma unroll
      for (int fn = 0; fn < 4; ++fn)
        acc[fm][fn] = MFMA16(af[fm], bfr[fn], acc[fm][fn]);
    if (++cur == 3) cur = 0;
  }

#pragma unroll
  for (int fm = 0; fm < 4; ++fm) {
    const int row0 = bm + wr + fm * 16 + lq * 4;
#pragma unroll
    for (int fn = 0; fn < 4; ++fn) {
      const int col = bn + wc + fn * 16 + lr;
      const float bb = bias[col];
      if (which == 2) {
        const int b = row0 >> 11, lrow = row0 & (CL - 1);
        const int hh = col >> 6, dh = col & 63;
        ushort4v pk;
#pragma unroll
        for (int j = 0; j < 4; ++j) pk[j] = f2bf(acc[fm][fn][j] + bb);
        *(ushort4v*)(Vt + (((size_t)((b * CH + hh) * CDH + dh)) << 11) + lrow) = pk;
      } else {
        unsigned short* outp = which == 0 ? Qp : Kp;
#pragma unroll
        for (int j = 0; j < 4; ++j)
          outp[(size_t)(row0 + j) * CD + col] = f2bf((acc[fm][fn][j] + bb) * alpha);
      }
    }
  }
}

// ---------------- final GEMM: out = X * Wc^T + bc (f32 out) --------------------

__global__ __launch_bounds__(256) void gemm_out(const unsigned short* __restrict__ A,
                                                const unsigned short* __restrict__ Bw,
                                                const float* __restrict__ bias,
                                                float* __restrict__ Cout) {
  __shared__ unsigned short Asm[3][128 * 32];
  __shared__ unsigned short Bsm[3][128 * 32];
  const int tid = threadIdx.x;
  const int w = tid >> 6, ln = tid & 63, lr = ln & 15, lq = ln >> 4;
  const int nbx = CD >> 7;
  const int cpx = (int)gridDim.x >> 3;
  const int bid = ((int)blockIdx.x & 7) * cpx + ((int)blockIdx.x >> 3);
  const int bm = (bid / nbx) << 7;
  const int bn = (bid % nbx) << 7;
  const int wr = (w >> 1) << 6, wc = (w & 1) << 6;  // wave tile 64x64

  f32x4 acc[4][4] = {};

  auto stage = [&](int buf, int k0) {
#pragma unroll
    for (int p = 0; p < 2; ++p) {
      const int idx = (p << 8) + (w << 6) + ln;
      const int row = idx >> 2, cc = (idx & 3) << 3;
      gld_lds16(A + (size_t)(bm + row) * CD + k0 + cc,
                (void*)(Asm[buf] + (size_t)((p << 8) + (w << 6)) * 8));
      gld_lds16(Bw + (size_t)(bn + row) * CD + k0 + cc,
                (void*)(Bsm[buf] + (size_t)((p << 8) + (w << 6)) * 8));
    }
  };

  stage(0, 0);
  stage(1, 32);

  const int nkt = CD >> 5;  // 32
  int cur = 0;
  for (int kt = 0; kt < nkt; ++kt) {
    GEMM_WAIT4(kt, nkt);
    if (kt + 2 < nkt) {
      int nb = cur + 2;
      if (nb >= 3) nb -= 3;
      stage(nb, (kt + 2) << 5);
    }
    bf16x8 af[4], bfr[4];
#pragma unroll
    for (int f = 0; f < 4; ++f) {
      af[f] = *(const bf16x8*)(Asm[cur] + ((wr + f * 16 + lr) * 32 + lq * 8));
      bfr[f] = *(const bf16x8*)(Bsm[cur] + ((wc + f * 16 + lr) * 32 + lq * 8));
    }
#pragma unroll
    for (int fm = 0; fm < 4; ++fm)
#pragma unroll
      for (int fn = 0; fn < 4; ++fn)
        acc[fm][fn] = MFMA16(af[fm], bfr[fn], acc[fm][fn]);
    if (++cur == 3) cur = 0;
  }

#pragma unroll
  for (int fm = 0; fm < 4; ++fm) {
    const int row0 = bm + wr + fm * 16 + lq * 4;
#pragma unroll
    for (int fn = 0; fn < 4; ++fn) {
      const int col = bn + wc + fn * 16 + lr;
      const float bb = bias[col];
#pragma unroll
      for (int j = 0; j < 4; ++j)
        Cout[(size_t)(row0 + j) * CD + col] = acc[fm][fn][j] + bb;
    }
  }
}

// ---------------- mean over L of each Vt row ----------------

__global__ __launch_bounds__(256) void meanv_kernel(const unsigned short* __restrict__ Vt,
                                                    float* __restrict__ meanv) {
  const int row = blockIdx.x * 4 + (threadIdx.x >> 6);
  const int ln = threadIdx.x & 63;
  const ushort8* p = (const ushort8*)(Vt + (size_t)row * CL);
  float s = 0.f;
#pragma unroll
  for (int it = 0; it < 4; ++it) {
    ushort8 v = p[it * 64 + ln];
#pragma unroll
    for (int j = 0; j < 8; ++j) s += bf2f(v[j]);
  }
#pragma unroll
  for (int off = 32; off; off >>= 1) s += __shfl_down(s, off);
  if (ln == 0) meanv[row] = s * (1.f / (float)CL);
}

// ---------------- attn_blk: 4-wave block, LDS-staged K/V, counted-vmcnt ring ----
// (R20 winner, byte-identical)

__global__ __launch_bounds__(256, 2) void attn_blk(const unsigned short* __restrict__ Qp,
                                                   const unsigned short* __restrict__ Kp,
                                                   const unsigned short* __restrict__ Vt,
                                                   const int* __restrict__ lens,
                                                   unsigned short* __restrict__ attno) {
  __shared__ unsigned short Ks[3][64 * 64];
  __shared__ unsigned short Vs[3][64 * 64];
  __shared__ unsigned short Ps[4][32][72];
  const int i = blockIdx.x;
  const int xcd = i & 7, bh8 = (i >> 3) & 7, slot = i >> 6;  // slot 0..15
  const int qt = 15 - slot;                                  // heavy first
  const int bh = bh8 * 8 + xcd;
  const int b = bh >> 4, h = bh & 15;
  const int qbase = qt << 7;
  const int len = lens[b];
  if (qbase >= len) return;  // whole block padded; padfix covers

  const int tid = threadIdx.x, w = tid >> 6, ln = tid & 63, lr = ln & 15, lq = ln >> 4;
  const int rowbase = qbase + (w << 5);     // this wave's 32 q-rows
  const int kdw = rowbase >> 6;             // wave's diagonal tile
  const int ntiles = 2 * qt + 2;            // block iterates tiles 0..2qt+1

  const unsigned short* Kbase = Kp + (size_t)(b * CL) * CD + h * 64;
  const unsigned short* Vbase = Vt + ((size_t)(bh * 64) << 11);
  const unsigned short* Qbase = Qp + (size_t)(b * CL + rowbase) * CD + h * 64;

  const int srow = (w << 4) + (ln >> 3);
  const int scol = (ln & 7) << 3;
  auto stage = [&](int buf, int kt) {
    const int kb = kt << 6;
#pragma unroll
    for (int p = 0; p < 2; ++p) {
      gld_lds16(Kbase + (size_t)(kb + srow + p * 8) * CD + scol,
                (void*)(Ks[buf] + (w << 10) + (p << 9)));
      gld_lds16(Vbase + (size_t)(srow + p * 8) * CL + kb + scol,
                (void*)(Vs[buf] + (w << 10) + (p << 9)));
    }
  };

  bf16x8 qa[2][2];
#pragma unroll
  for (int rs = 0; rs < 2; ++rs)
#pragma unroll
    for (int hf = 0; hf < 2; ++hf)
      qa[rs][hf] = *(const bf16x8*)(Qbase + (size_t)(rs * 16 + lr) * CD + hf * 32 + lq * 8);
  __builtin_amdgcn_sched_barrier(0);
  stage(0, 0);
  __builtin_amdgcn_sched_barrier(0);
  stage(1, 1);
  __builtin_amdgcn_sched_barrier(0);

  f32x4 o[2][4] = {};
  float lsum[2][4] = {};

  int cur = 0;
  for (int kt = 0; kt < ntiles; ++kt) {
    if (kt + 1 < ntiles)
      asm volatile("s_waitcnt vmcnt(4)" ::: "memory");
    else
      asm volatile("s_waitcnt vmcnt(0)" ::: "memory");
    __builtin_amdgcn_s_barrier();
    asm volatile("" ::: "memory");
    if (kt + 2 < ntiles) {
      int nb = cur + 2;
      if (nb >= 3) nb -= 3;
      stage(nb, kt + 2);
    }

    if (kt <= kdw) {
      const bool dm = (kt == kdw);
      const int kb = kt << 6;
      const unsigned short* Kc = Ks[cur];
      const unsigned short* Vc = Vs[cur];

      bf16x8 kf[4][2];
#pragma unroll
      for (int cf = 0; cf < 4; ++cf)
#pragma unroll
        for (int hf = 0; hf < 2; ++hf)
          kf[cf][hf] = *(const bf16x8*)(Kc + (cf * 16 + lr) * 64 + hf * 32 + lq * 8);

#pragma unroll
      for (int rs = 0; rs < 2; ++rs) {
        f32x4 s_[4];
#pragma unroll
        for (int cf = 0; cf < 4; ++cf) {
          f32x4 z = {};
          z = MFMA16(qa[rs][0], kf[cf][0], z);
          z = MFMA16(qa[rs][1], kf[cf][1], z);
          s_[cf] = z;
        }
#pragma unroll
        for (int cf = 0; cf < 4; ++cf) {
#pragma unroll
          for (int j = 0; j < 4; ++j) {
            float p = __builtin_amdgcn_exp2f(s_[cf][j]);
            if (dm) {
              const int key = kb + cf * 16 + lr;
              const int row = rowbase + rs * 16 + lq * 4 + j;
              p = (key > row) ? 0.f : p;
            }
            lsum[rs][j] += p;
            Ps[w][rs * 16 + lq * 4 + j][cf * 16 + lr] =
                (unsigned short)(__builtin_bit_cast(unsigned int, p) >> 16);
          }
        }
      }

      bf16x8 pa[2][2];
#pragma unroll
      for (int rs = 0; rs < 2; ++rs)
#pragma unroll
        for (int hf = 0; hf < 2; ++hf)
          pa[rs][hf] = *(const bf16x8*)(&Ps[w][rs * 16 + lr][hf * 32 + lq * 8]);

#pragma unroll
      for (int df = 0; df < 4; ++df) {
        const bf16x8 vb0 = *(const bf16x8*)(Vc + (df * 16 + lr) * 64 + lq * 8);
        const bf16x8 vb1 = *(const bf16x8*)(Vc + (df * 16 + lr) * 64 + 32 + lq * 8);
        o[0][df] = MFMA16(pa[0][0], vb0, o[0][df]);
        o[0][df] = MFMA16(pa[0][1], vb1, o[0][df]);
        o[1][df] = MFMA16(pa[1][0], vb0, o[1][df]);
        o[1][df] = MFMA16(pa[1][1], vb1, o[1][df]);
      }
    }
    if (++cur == 3) cur = 0;
  }

  float inv[2][4];
#pragma unroll
  for (int rs = 0; rs < 2; ++rs)
#pragma unroll
    for (int j = 0; j < 4; ++j) {
      float t = lsum[rs][j];
      t += __shfl_xor(t, 1);
      t += __shfl_xor(t, 2);
      t += __shfl_xor(t, 4);
      t += __shfl_xor(t, 8);
      inv[rs][j] = __builtin_amdgcn_rcpf(t);
    }

#pragma unroll
  for (int rs = 0; rs < 2; ++rs)
#pragma unroll
    for (int df = 0; df < 4; ++df)
#pragma unroll
      for (int j = 0; j < 4; ++j)
        attno[(size_t)(b * CL + rowbase + rs * 16 + lq * 4 + j) * CD + h * 64 + df * 16 +
              lr] = f2bf(o[rs][df][j] * inv[rs][j]);
}

// ---------------- attn_fb: R10/R16 32-row single-deep body (stable fallback) ---

#define LOADK(kt, dst)                                                              \
  {                                                                                 \
    const int kb_ = (kt) << 6;                                                      \
    for (int cf_ = 0; cf_ < 4; ++cf_)                                               \
      for (int hf_ = 0; hf_ < 2; ++hf_)                                             \
        dst[cf_][hf_] = *(const bf16x8*)(Kbase + (size_t)(kb_ + cf_ * 16 + lr) * CD + \
                                         hf_ * 32 + lq * 8);                        \
  }

#define VLOAD_FB(kt, dst)                                                           \
  {                                                                                 \
    const int kb_ = (kt) << 6;                                                      \
    for (int df_ = 0; df_ < 4; ++df_)                                               \
      for (int hf_ = 0; hf_ < 2; ++hf_)                                             \
        dst[df_][hf_] = *(const bf16x8*)(Vbase + (((size_t)(df_ * 16 + lr)) << 11) +  \
                                         kb_ + hf_ * 32 + lq * 8);                  \
  }

#define TILE_FB(kt, KF, KN)                                                         \
  {                                                                                 \
    const bool dm_ = (kt) == kdiag;                                                 \
    const int kb_ = (kt) << 6;                                                      \
    f32x4 s_[2][4];                                                                 \
    for (int rs_ = 0; rs_ < 2; ++rs_)                                               \
      for (int cf_ = 0; cf_ < 4; ++cf_) {                                           \
        f32x4 z_ = {};                                                              \
        z_ = MFMA16(qa[rs_][0], KF[cf_][0], z_);                                    \
        z_ = MFMA16(qa[rs_][1], KF[cf_][1], z_);                                    \
        s_[rs_][cf_] = z_;                                                          \
      }                                                                             \
    VLOAD_FB(kt, vb);                                                               \
    if ((kt) < kdiag) LOADK((kt) + 1, KN);                                          \
    __builtin_amdgcn_sched_barrier(0);                                              \
    for (int rs_ = 0; rs_ < 2; ++rs_)                                               \
      for (int cf_ = 0; cf_ < 4; ++cf_)                                             \
        for (int j_ = 0; j_ < 4; ++j_) {                                            \
          float p_ = __builtin_amdgcn_exp2f(s_[rs_][cf_][j_]);                      \
          if (dm_) {                                                                \
            const int key_ = kb_ + cf_ * 16 + lr;                                   \
            const int row_ = rowbase + rs_ * 16 + lq * 4 + j_;                      \
            p_ = (key_ > row_) ? 0.f : p_;                                          \
          }                                                                         \
          lsum[rs_][j_] += p_;                                                      \
          Ps[rs_ * 16 + lq * 4 + j_][cf_ * 16 + lr] =                               \
              (unsigned short)(__builtin_bit_cast(unsigned int, p_) >> 16);         \
        }                                                                           \
    bf16x8 pa_[2][2];                                                               \
    for (int rs_ = 0; rs_ < 2; ++rs_)                                               \
      for (int hf_ = 0; hf_ < 2; ++hf_)                                             \
        pa_[rs_][hf_] = *(const bf16x8*)(&Ps[rs_ * 16 + lr][hf_ * 32 + lq * 8]);    \
    for (int df_ = 0; df_ < 4; ++df_) {                                             \
      o[0][df_] = MFMA16(pa_[0][0], vb[df_][0], o[0][df_]);                         \
      o[0][df_] = MFMA16(pa_[0][1], vb[df_][1], o[0][df_]);                         \
      o[1][df_] = MFMA16(pa_[1][0], vb[df_][0], o[1][df_]);                         \
      o[1][df_] = MFMA16(pa_[1][1], vb[df_][1], o[1][df_]);                         \
    }                                                                               \
  }

__global__ __launch_bounds__(64, 2) void attn_fb(const unsigned short* __restrict__ Qp,
                                                 const unsigned short* __restrict__ Kp,
                                                 const unsigned short* __restrict__ Vt,
                                                 const int* __restrict__ lens,
                                                 unsigned short* __restrict__ attno) {
  __shared__ unsigned short Ps[32][72];
  const int i = blockIdx.x;
  const int xcd = i & 7, bh8 = (i >> 3) & 7, slot = i >> 6;  // slot 0..63
  const int qt = 15 - (slot >> 2), wv = slot & 3;            // heavy first
  const int bh = bh8 * 8 + xcd;
  const int b = bh >> 4, h = bh & 15;
  const int rowbase = (qt << 7) + (wv << 5);
  const int len = lens[b];
  if (rowbase >= len) return;  // rows handled by padfix

  const int tid = threadIdx.x, lr = tid & 15, lq = tid >> 4;

  const unsigned short* Kbase = Kp + (size_t)(b * CL) * CD + h * 64;
  const unsigned short* Vbase = Vt + ((size_t)(bh * 64) << 11);
  const unsigned short* Qbase = Qp + (size_t)(b * CL + rowbase) * CD + h * 64;

  bf16x8 qa[2][2];
#pragma unroll
  for (int rs = 0; rs < 2; ++rs)
#pragma unroll
    for (int hf = 0; hf < 2; ++hf)
      qa[rs][hf] = *(const bf16x8*)(Qbase + (size_t)(rs * 16 + lr) * CD + hf * 32 + lq * 8);

  f32x4 o[2][4] = {};
  float lsum[2][4] = {};
  const int kdiag = rowbase >> 6;

  bf16x8 kfA[4][2], kfB[4][2], vb[4][2];
  LOADK(0, kfA);

  int kt = 0;
  while (true) {
    TILE_FB(kt, kfA, kfB);
    if (kt == kdiag) break;
    ++kt;
    TILE_FB(kt, kfB, kfA);
    if (kt == kdiag) break;
    ++kt;
  }

  float inv[2][4];
#pragma unroll
  for (int rs = 0; rs < 2; ++rs)
#pragma unroll
    for (int j = 0; j < 4; ++j) {
      float t = lsum[rs][j];
      t += __shfl_xor(t, 1);
      t += __shfl_xor(t, 2);
      t += __shfl_xor(t, 4);
      t += __shfl_xor(t, 8);
      inv[rs][j] = __builtin_amdgcn_rcpf(t);
    }

#pragma unroll
  for (int rs = 0; rs < 2; ++rs)
#pragma unroll
    for (int df = 0; df < 4; ++df)
#pragma unroll
      for (int j = 0; j < 4; ++j)
        attno[(size_t)(b * CL + rowbase + rs * 16 + lq * 4 + j) * CD + h * 64 + df * 16 +
              lr] = f2bf(o[rs][df][j] * inv[rs][j]);
}

// ---------------- padded-query fixup: uniform attention = mean of V rows -------

__global__ __launch_bounds__(256) void padfix_kernel(const int* __restrict__ lens,
                                                     const float* __restrict__ meanv,
                                                     unsigned short* __restrict__ attno) {
  const int q = blockIdx.x & (CL - 1);
  const int b = blockIdx.x >> 11;
  if (q < lens[b]) return;
#pragma unroll
  for (int i = 0; i < 4; ++i) {
    const int col = threadIdx.x + i * 256;
    attno[(size_t)(b * CL + q) * CD + col] = f2bf(meanv[b * CD + col]);
  }
}

// ---------------- launch ----------------

extern "C" void kernel_launch(void* const* d_in, const int* in_sizes, int n_in,
                              void* d_out, int out_size, void* d_ws, size_t ws_size,
                              hipStream_t stream) {
  const float* q  = (const float*)d_in[0];
  const float* k  = (const float*)d_in[1];
  const float* v  = (const float*)d_in[2];
  const int*   am = (const int*)d_in[3];
  const float* Wq = (const float*)d_in[4];
  const float* bq = (const float*)d_in[5];
  const float* Wk = (const float*)d_in[6];
  const float* bk = (const float*)d_in[7];
  const float* Wv = (const float*)d_in[8];
  const float* bv = (const float*)d_in[9];
  const float* Wc = (const float*)d_in[10];
  const float* bc = (const float*)d_in[11];
  float* out = (float*)d_out;

  unsigned short* Wqb = (unsigned short*)d_ws;   // Wqb|Wkb|Wvb|Wcb contiguous
  unsigned short* Wkb = Wqb + (1 << 20);
  unsigned short* Wvb = Wkb + (1 << 20);
  unsigned short* Wcb = Wvb + (1 << 20);
  unsigned short* Xq  = Wcb + (1 << 20);          // also attn-out (X aliases Xq)
  unsigned short* Xk  = Xq + (size_t)CM * CD;
  unsigned short* Xv  = Xk + (size_t)CM * CD;
  unsigned short* Qp  = Xv + (size_t)CM * CD;
  unsigned short* Kp  = Qp + (size_t)CM * CD;
  unsigned short* Vt  = Kp + (size_t)CM * CD;     // [B,H,DH,L]
  float* meanv = (float*)(Vt + (size_t)CM * CD);  // [B, D]
  int* lens = (int*)(meanv + CB * CD);
  unsigned short* X = Xq;

  lens_kernel<<<CB, 256, 0, stream>>>(am, lens);
  cvt_all<<<14336, 256, 0, stream>>>(q, k, v, Wq, Wk, Wv, Wc, Xq, Xk, Xv,
                                     Wqb, Wkb, Wvb, Wcb);

  const float QSCALE = 0.125f * 1.44269504f;  // folded 1/sqrt(DH) * log2(e)

  gemm_qkv<<<1536, 256, 0, stream>>>(Xq, Xk, Xv, Wqb, bq, bk, bv, Qp, Kp, Vt, QSCALE);

  meanv_kernel<<<1024, 256, 0, stream>>>(Vt, meanv);

  // spill-guard (R16 pattern): use the LDS-ring block kernel only if spill-free.
  hipFuncAttributes fa{};
  bool blk_ok = false;
  if (hipFuncGetAttributes(&fa, (const void*)attn_blk) == hipSuccess)
    blk_ok = (fa.localSizeBytes == 0);
  if (blk_ok)
    attn_blk<<<1024, 256, 0, stream>>>(Qp, Kp, Vt, lens, X);
  else
    attn_fb<<<4096, 64, 0, stream>>>(Qp, Kp, Vt, lens, X);

  padfix_kernel<<<CB * CL, 256, 0, stream>>>(lens, meanv, X);

  gemm_out<<<512, 256, 0, stream>>>(X, Wcb, bc, out);
}

// Round 22
// 191.423 us; speedup vs baseline: 1.0757x; 1.0757x over previous
//
#include <hip/hip_runtime.h>
#include <stdint.h>

typedef __bf16 bf16x8 __attribute__((ext_vector_type(8)));
typedef float f32x4 __attribute__((ext_vector_type(4)));
typedef unsigned short ushort8 __attribute__((ext_vector_type(8)));
typedef unsigned short ushort4v __attribute__((ext_vector_type(4)));

constexpr int CB = 4;
constexpr int CL = 2048;
constexpr int CD = 1024;
constexpr int CH = 16;
constexpr int CDH = 64;
constexpr int CM = CB * CL;  // 8192

__device__ __forceinline__ unsigned short f2bf(float f) {
  union { float f; unsigned u; } x; x.f = f;
  unsigned r = x.u + 0x7fffu + ((x.u >> 16) & 1u);
  return (unsigned short)(r >> 16);
}
__device__ __forceinline__ float bf2f(unsigned short b) {
  union { unsigned u; float f; } x; x.u = ((unsigned)b) << 16;
  return x.f;
}

__device__ __forceinline__ void gld_lds16(const void* g, void* l) {
  __builtin_amdgcn_global_load_lds((const __attribute__((address_space(1))) void*)g,
                                   (__attribute__((address_space(3))) void*)l, 16, 0, 0);
}

#define MFMA16(a, b, c) __builtin_amdgcn_mfma_f32_16x16x32_bf16((a), (b), (c), 0, 0, 0)

// ---------------- fp32 -> bf16: weights + q/k/v in ONE launch ------------------

__global__ __launch_bounds__(256) void cvt_all(const float* __restrict__ q,
                                               const float* __restrict__ k,
                                               const float* __restrict__ v,
                                               const float* __restrict__ Wq,
                                               const float* __restrict__ Wk,
                                               const float* __restrict__ Wv,
                                               const float* __restrict__ Wc,
                                               unsigned short* __restrict__ oq,
                                               unsigned short* __restrict__ ok,
                                               unsigned short* __restrict__ ov,
                                               unsigned short* __restrict__ oWq,
                                               unsigned short* __restrict__ oWk,
                                               unsigned short* __restrict__ oWv,
                                               unsigned short* __restrict__ oWc) {
  int bi = blockIdx.x;
  const float* s;
  unsigned short* d;
  int i;
  if (bi < 2048) {
    const int w = bi >> 9;
    i = (bi & 511) * 256 + threadIdx.x;
    s = w == 0 ? Wq : w == 1 ? Wk : w == 2 ? Wv : Wc;
    d = w == 0 ? oWq : w == 1 ? oWk : w == 2 ? oWv : oWc;
  } else {
    bi -= 2048;
    const int w = bi >> 12;
    i = (bi & 4095) * 256 + threadIdx.x;
    s = w == 0 ? q : w == 1 ? k : v;
    d = w == 0 ? oq : w == 1 ? ok : ov;
  }
  const float4* sp = (const float4*)s;
  float4 a = sp[2 * i], b = sp[2 * i + 1];
  ushort8 o;
  o[0] = f2bf(a.x); o[1] = f2bf(a.y); o[2] = f2bf(a.z); o[3] = f2bf(a.w);
  o[4] = f2bf(b.x); o[5] = f2bf(b.y); o[6] = f2bf(b.z); o[7] = f2bf(b.w);
  ((ushort8*)d)[i] = o;
}

// ---------------- lengths from prefix mask ----------------

__global__ __launch_bounds__(256) void lens_kernel(const int* __restrict__ mask,
                                                   int* __restrict__ lens) {
  __shared__ int part[4];
  const int b = blockIdx.x;
  int cnt = 0;
  for (int i = threadIdx.x; i < CL; i += 256) cnt += (mask[b * CL + i] != 0) ? 1 : 0;
#pragma unroll
  for (int off = 32; off; off >>= 1) cnt += __shfl_down(cnt, off);
  if ((threadIdx.x & 63) == 0) part[threadIdx.x >> 6] = cnt;
  __syncthreads();
  if (threadIdx.x == 0) lens[b] = part[0] + part[1] + part[2] + part[3];
}

// ---------------- GEMM pipeline: R20 8-wave 3-ring + T2 XOR swizzle ------------
// LDS stays linear (global_load_lds dest must be base+lane*16); the SOURCE
// chunk is pre-swizzled (c_src = c' ^ ((row>>1)&3)) and every fragment read
// applies the same involution (chunk' = lq ^ ((row>>1)&3)). Lane->slot map
// becomes a Latin square over the 8 16B-slots of the 128B bank ring: 8-way
// aliasing -> 2-way (free). Rule #21: both sides, same involution.

#define GEMM_WAIT2(kt, nkt)                                             \
  {                                                                     \
    if ((kt) + 1 < (nkt))                                               \
      asm volatile("s_waitcnt vmcnt(2)" ::: "memory");                  \
    else                                                                \
      asm volatile("s_waitcnt vmcnt(0)" ::: "memory");                  \
    __builtin_amdgcn_s_barrier();                                       \
    asm volatile("" ::: "memory");                                      \
  }

// ---------------- fused QKV GEMM (bf16 A via global_load_lds), N = 3072 --------

__global__ __launch_bounds__(512) void gemm_qkv(const unsigned short* __restrict__ Xq,
                                                const unsigned short* __restrict__ Xk,
                                                const unsigned short* __restrict__ Xv,
                                                const unsigned short* __restrict__ Wb,
                                                const float* __restrict__ bq,
                                                const float* __restrict__ bk,
                                                const float* __restrict__ bv,
                                                unsigned short* __restrict__ Qp,
                                                unsigned short* __restrict__ Kp,
                                                unsigned short* __restrict__ Vt,
                                                float qscale) {
  __shared__ unsigned short Asm[3][128 * 32];
  __shared__ unsigned short Bsm[3][128 * 32];
  const int tid = threadIdx.x;
  const int w = tid >> 6, ln = tid & 63, lr = ln & 15, lq = ln >> 4;
  const int nbx = 24;  // 3072/128
  const int cpx = (int)gridDim.x >> 3;
  const int bid = ((int)blockIdx.x & 7) * cpx + ((int)blockIdx.x >> 3);
  const int bm = (bid / nbx) << 7;
  const int bnG = (bid % nbx) << 7;
  const int which = bnG >> 10, bn = bnG & 1023;
  const unsigned short* A = which == 0 ? Xq : which == 1 ? Xk : Xv;
  const unsigned short* Bw = Wb + ((size_t)which << 20);
  const float* bias = which == 0 ? bq : which == 1 ? bk : bv;
  const float alpha = which == 0 ? qscale : 1.0f;
  const int wr = (w >> 1) << 5, wc = (w & 1) << 6;   // wave tile 32x64

  f32x4 acc[2][4] = {};
  const int arow = tid >> 2;
  const int akc = (((tid & 3) ^ ((arow >> 1) & 3)) << 3);  // pre-swizzled source chunk

  auto stage = [&](int buf, int k0) {
    gld_lds16(A + (size_t)(bm + arow) * CD + k0 + akc, (void*)(Asm[buf] + w * 512));
    gld_lds16(Bw + (size_t)(bn + arow) * CD + k0 + akc, (void*)(Bsm[buf] + w * 512));
  };

  stage(0, 0);
  stage(1, 32);

  const int nkt = CD >> 5;  // 32
  int cur = 0;
  for (int kt = 0; kt < nkt; ++kt) {
    GEMM_WAIT2(kt, nkt);
    if (kt + 2 < nkt) {
      int nb = cur + 2;
      if (nb >= 3) nb -= 3;
      stage(nb, (kt + 2) << 5);
    }
    bf16x8 af[2], bfr[4];
#pragma unroll
    for (int f = 0; f < 2; ++f) {
      const int R = wr + f * 16 + lr;
      af[f] = *(const bf16x8*)(Asm[cur] + (R * 32 + ((lq ^ ((R >> 1) & 3)) << 3)));
    }
#pragma unroll
    for (int f = 0; f < 4; ++f) {
      const int R = wc + f * 16 + lr;
      bfr[f] = *(const bf16x8*)(Bsm[cur] + (R * 32 + ((lq ^ ((R >> 1) & 3)) << 3)));
    }
#pragma unroll
    for (int fm = 0; fm < 2; ++fm)
#pragma unroll
      for (int fn = 0; fn < 4; ++fn)
        acc[fm][fn] = MFMA16(af[fm], bfr[fn], acc[fm][fn]);
    if (++cur == 3) cur = 0;
  }

#pragma unroll
  for (int fm = 0; fm < 2; ++fm) {
    const int row0 = bm + wr + fm * 16 + lq * 4;
#pragma unroll
    for (int fn = 0; fn < 4; ++fn) {
      const int col = bn + wc + fn * 16 + lr;
      const float bb = bias[col];
      if (which == 2) {
        const int b = row0 >> 11, lrow = row0 & (CL - 1);
        const int hh = col >> 6, dh = col & 63;
        ushort4v pk;
#pragma unroll
        for (int j = 0; j < 4; ++j) pk[j] = f2bf(acc[fm][fn][j] + bb);
        *(ushort4v*)(Vt + (((size_t)((b * CH + hh) * CDH + dh)) << 11) + lrow) = pk;
      } else {
        unsigned short* outp = which == 0 ? Qp : Kp;
#pragma unroll
        for (int j = 0; j < 4; ++j)
          outp[(size_t)(row0 + j) * CD + col] = f2bf((acc[fm][fn][j] + bb) * alpha);
      }
    }
  }
}

// ---------------- final GEMM: out = X * Wc^T + bc (f32 out) --------------------

__global__ __launch_bounds__(512) void gemm_out(const unsigned short* __restrict__ A,
                                                const unsigned short* __restrict__ Bw,
                                                const float* __restrict__ bias,
                                                float* __restrict__ Cout) {
  __shared__ unsigned short Asm[3][128 * 32];
  __shared__ unsigned short Bsm[3][128 * 32];
  const int tid = threadIdx.x;
  const int w = tid >> 6, ln = tid & 63, lr = ln & 15, lq = ln >> 4;
  const int nbx = CD >> 7;
  const int cpx = (int)gridDim.x >> 3;
  const int bid = ((int)blockIdx.x & 7) * cpx + ((int)blockIdx.x >> 3);
  const int bm = (bid / nbx) << 7;
  const int bn = (bid % nbx) << 7;
  const int wr = (w >> 1) << 5, wc = (w & 1) << 6;

  f32x4 acc[2][4] = {};
  const int arow = tid >> 2;
  const int akc = (((tid & 3) ^ ((arow >> 1) & 3)) << 3);

  auto stage = [&](int buf, int k0) {
    gld_lds16(A + (size_t)(bm + arow) * CD + k0 + akc, (void*)(Asm[buf] + w * 512));
    gld_lds16(Bw + (size_t)(bn + arow) * CD + k0 + akc, (void*)(Bsm[buf] + w * 512));
  };

  stage(0, 0);
  stage(1, 32);

  const int nkt = CD >> 5;  // 32
  int cur = 0;
  for (int kt = 0; kt < nkt; ++kt) {
    GEMM_WAIT2(kt, nkt);
    if (kt + 2 < nkt) {
      int nb = cur + 2;
      if (nb >= 3) nb -= 3;
      stage(nb, (kt + 2) << 5);
    }
    bf16x8 af[2], bfr[4];
#pragma unroll
    for (int f = 0; f < 2; ++f) {
      const int R = wr + f * 16 + lr;
      af[f] = *(const bf16x8*)(Asm[cur] + (R * 32 + ((lq ^ ((R >> 1) & 3)) << 3)));
    }
#pragma unroll
    for (int f = 0; f < 4; ++f) {
      const int R = wc + f * 16 + lr;
      bfr[f] = *(const bf16x8*)(Bsm[cur] + (R * 32 + ((lq ^ ((R >> 1) & 3)) << 3)));
    }
#pragma unroll
    for (int fm = 0; fm < 2; ++fm)
#pragma unroll
      for (int fn = 0; fn < 4; ++fn)
        acc[fm][fn] = MFMA16(af[fm], bfr[fn], acc[fm][fn]);
    if (++cur == 3) cur = 0;
  }

#pragma unroll
  for (int fm = 0; fm < 2; ++fm) {
    const int row0 = bm + wr + fm * 16 + lq * 4;
#pragma unroll
    for (int fn = 0; fn < 4; ++fn) {
      const int col = bn + wc + fn * 16 + lr;
      const float bb = bias[col];
#pragma unroll
      for (int j = 0; j < 4; ++j)
        Cout[(size_t)(row0 + j) * CD + col] = acc[fm][fn][j] + bb;
    }
  }
}

// ---------------- mean over L of each Vt row ----------------

__global__ __launch_bounds__(256) void meanv_kernel(const unsigned short* __restrict__ Vt,
                                                    float* __restrict__ meanv) {
  const int row = blockIdx.x * 4 + (threadIdx.x >> 6);
  const int ln = threadIdx.x & 63;
  const ushort8* p = (const ushort8*)(Vt + (size_t)row * CL);
  float s = 0.f;
#pragma unroll
  for (int it = 0; it < 4; ++it) {
    ushort8 v = p[it * 64 + ln];
#pragma unroll
    for (int j = 0; j < 8; ++j) s += bf2f(v[j]);
  }
#pragma unroll
  for (int off = 32; off; off >>= 1) s += __shfl_down(s, off);
  if (ln == 0) meanv[row] = s * (1.f / (float)CL);
}

// ---------------- attn_blk: 4-wave block, LDS-staged K/V, counted-vmcnt ring ----
// (R20 winner, byte-identical)

__global__ __launch_bounds__(256, 2) void attn_blk(const unsigned short* __restrict__ Qp,
                                                   const unsigned short* __restrict__ Kp,
                                                   const unsigned short* __restrict__ Vt,
                                                   const int* __restrict__ lens,
                                                   unsigned short* __restrict__ attno) {
  __shared__ unsigned short Ks[3][64 * 64];
  __shared__ unsigned short Vs[3][64 * 64];
  __shared__ unsigned short Ps[4][32][72];
  const int i = blockIdx.x;
  const int xcd = i & 7, bh8 = (i >> 3) & 7, slot = i >> 6;  // slot 0..15
  const int qt = 15 - slot;                                  // heavy first
  const int bh = bh8 * 8 + xcd;
  const int b = bh >> 4, h = bh & 15;
  const int qbase = qt << 7;
  const int len = lens[b];
  if (qbase >= len) return;  // whole block padded; padfix covers

  const int tid = threadIdx.x, w = tid >> 6, ln = tid & 63, lr = ln & 15, lq = ln >> 4;
  const int rowbase = qbase + (w << 5);     // this wave's 32 q-rows
  const int kdw = rowbase >> 6;             // wave's diagonal tile
  const int ntiles = 2 * qt + 2;            // block iterates tiles 0..2qt+1

  const unsigned short* Kbase = Kp + (size_t)(b * CL) * CD + h * 64;
  const unsigned short* Vbase = Vt + ((size_t)(bh * 64) << 11);
  const unsigned short* Qbase = Qp + (size_t)(b * CL + rowbase) * CD + h * 64;

  const int srow = (w << 4) + (ln >> 3);
  const int scol = (ln & 7) << 3;
  auto stage = [&](int buf, int kt) {
    const int kb = kt << 6;
#pragma unroll
    for (int p = 0; p < 2; ++p) {
      gld_lds16(Kbase + (size_t)(kb + srow + p * 8) * CD + scol,
                (void*)(Ks[buf] + (w << 10) + (p << 9)));
      gld_lds16(Vbase + (size_t)(srow + p * 8) * CL + kb + scol,
                (void*)(Vs[buf] + (w << 10) + (p << 9)));
    }
  };

  bf16x8 qa[2][2];
#pragma unroll
  for (int rs = 0; rs < 2; ++rs)
#pragma unroll
    for (int hf = 0; hf < 2; ++hf)
      qa[rs][hf] = *(const bf16x8*)(Qbase + (size_t)(rs * 16 + lr) * CD + hf * 32 + lq * 8);
  __builtin_amdgcn_sched_barrier(0);
  stage(0, 0);
  __builtin_amdgcn_sched_barrier(0);
  stage(1, 1);
  __builtin_amdgcn_sched_barrier(0);

  f32x4 o[2][4] = {};
  float lsum[2][4] = {};

  int cur = 0;
  for (int kt = 0; kt < ntiles; ++kt) {
    if (kt + 1 < ntiles)
      asm volatile("s_waitcnt vmcnt(4)" ::: "memory");
    else
      asm volatile("s_waitcnt vmcnt(0)" ::: "memory");
    __builtin_amdgcn_s_barrier();
    asm volatile("" ::: "memory");
    if (kt + 2 < ntiles) {
      int nb = cur + 2;
      if (nb >= 3) nb -= 3;
      stage(nb, kt + 2);
    }

    if (kt <= kdw) {
      const bool dm = (kt == kdw);
      const int kb = kt << 6;
      const unsigned short* Kc = Ks[cur];
      const unsigned short* Vc = Vs[cur];

      bf16x8 kf[4][2];
#pragma unroll
      for (int cf = 0; cf < 4; ++cf)
#pragma unroll
        for (int hf = 0; hf < 2; ++hf)
          kf[cf][hf] = *(const bf16x8*)(Kc + (cf * 16 + lr) * 64 + hf * 32 + lq * 8);

#pragma unroll
      for (int rs = 0; rs < 2; ++rs) {
        f32x4 s_[4];
#pragma unroll
        for (int cf = 0; cf < 4; ++cf) {
          f32x4 z = {};
          z = MFMA16(qa[rs][0], kf[cf][0], z);
          z = MFMA16(qa[rs][1], kf[cf][1], z);
          s_[cf] = z;
        }
#pragma unroll
        for (int cf = 0; cf < 4; ++cf) {
#pragma unroll
          for (int j = 0; j < 4; ++j) {
            float p = __builtin_amdgcn_exp2f(s_[cf][j]);
            if (dm) {
              const int key = kb + cf * 16 + lr;
              const int row = rowbase + rs * 16 + lq * 4 + j;
              p = (key > row) ? 0.f : p;
            }
            lsum[rs][j] += p;
            Ps[w][rs * 16 + lq * 4 + j][cf * 16 + lr] =
                (unsigned short)(__builtin_bit_cast(unsigned int, p) >> 16);
          }
        }
      }

      bf16x8 pa[2][2];
#pragma unroll
      for (int rs = 0; rs < 2; ++rs)
#pragma unroll
        for (int hf = 0; hf < 2; ++hf)
          pa[rs][hf] = *(const bf16x8*)(&Ps[w][rs * 16 + lr][hf * 32 + lq * 8]);

#pragma unroll
      for (int df = 0; df < 4; ++df) {
        const bf16x8 vb0 = *(const bf16x8*)(Vc + (df * 16 + lr) * 64 + lq * 8);
        const bf16x8 vb1 = *(const bf16x8*)(Vc + (df * 16 + lr) * 64 + 32 + lq * 8);
        o[0][df] = MFMA16(pa[0][0], vb0, o[0][df]);
        o[0][df] = MFMA16(pa[0][1], vb1, o[0][df]);
        o[1][df] = MFMA16(pa[1][0], vb0, o[1][df]);
        o[1][df] = MFMA16(pa[1][1], vb1, o[1][df]);
      }
    }
    if (++cur == 3) cur = 0;
  }

  float inv[2][4];
#pragma unroll
  for (int rs = 0; rs < 2; ++rs)
#pragma unroll
    for (int j = 0; j < 4; ++j) {
      float t = lsum[rs][j];
      t += __shfl_xor(t, 1);
      t += __shfl_xor(t, 2);
      t += __shfl_xor(t, 4);
      t += __shfl_xor(t, 8);
      inv[rs][j] = __builtin_amdgcn_rcpf(t);
    }

#pragma unroll
  for (int rs = 0; rs < 2; ++rs)
#pragma unroll
    for (int df = 0; df < 4; ++df)
#pragma unroll
      for (int j = 0; j < 4; ++j)
        attno[(size_t)(b * CL + rowbase + rs * 16 + lq * 4 + j) * CD + h * 64 + df * 16 +
              lr] = f2bf(o[rs][df][j] * inv[rs][j]);
}

// ---------------- attn_fb: R10/R16 32-row single-deep body (stable fallback) ---

#define LOADK(kt, dst)                                                              \
  {                                                                                 \
    const int kb_ = (kt) << 6;                                                      \
    for (int cf_ = 0; cf_ < 4; ++cf_)                                               \
      for (int hf_ = 0; hf_ < 2; ++hf_)                                             \
        dst[cf_][hf_] = *(const bf16x8*)(Kbase + (size_t)(kb_ + cf_ * 16 + lr) * CD + \
                                         hf_ * 32 + lq * 8);                        \
  }

#define VLOAD_FB(kt, dst)                                                           \
  {                                                                                 \
    const int kb_ = (kt) << 6;                                                      \
    for (int df_ = 0; df_ < 4; ++df_)                                               \
      for (int hf_ = 0; hf_ < 2; ++hf_)                                             \
        dst[df_][hf_] = *(const bf16x8*)(Vbase + (((size_t)(df_ * 16 + lr)) << 11) +  \
                                         kb_ + hf_ * 32 + lq * 8);                  \
  }

#define TILE_FB(kt, KF, KN)                                                         \
  {                                                                                 \
    const bool dm_ = (kt) == kdiag;                                                 \
    const int kb_ = (kt) << 6;                                                      \
    f32x4 s_[2][4];                                                                 \
    for (int rs_ = 0; rs_ < 2; ++rs_)                                               \
      for (int cf_ = 0; cf_ < 4; ++cf_) {                                           \
        f32x4 z_ = {};                                                              \
        z_ = MFMA16(qa[rs_][0], KF[cf_][0], z_);                                    \
        z_ = MFMA16(qa[rs_][1], KF[cf_][1], z_);                                    \
        s_[rs_][cf_] = z_;                                                          \
      }                                                                             \
    VLOAD_FB(kt, vb);                                                               \
    if ((kt) < kdiag) LOADK((kt) + 1, KN);                                          \
    __builtin_amdgcn_sched_barrier(0);                                              \
    for (int rs_ = 0; rs_ < 2; ++rs_)                                               \
      for (int cf_ = 0; cf_ < 4; ++cf_)                                             \
        for (int j_ = 0; j_ < 4; ++j_) {                                            \
          float p_ = __builtin_amdgcn_exp2f(s_[rs_][cf_][j_]);                      \
          if (dm_) {                                                                \
            const int key_ = kb_ + cf_ * 16 + lr;                                   \
            const int row_ = rowbase + rs_ * 16 + lq * 4 + j_;                      \
            p_ = (key_ > row_) ? 0.f : p_;                                          \
          }                                                                         \
          lsum[rs_][j_] += p_;                                                      \
          Ps[rs_ * 16 + lq * 4 + j_][cf_ * 16 + lr] =                               \
              (unsigned short)(__builtin_bit_cast(unsigned int, p_) >> 16);         \
        }                                                                           \
    bf16x8 pa_[2][2];                                                               \
    for (int rs_ = 0; rs_ < 2; ++rs_)                                               \
      for (int hf_ = 0; hf_ < 2; ++hf_)                                             \
        pa_[rs_][hf_] = *(const bf16x8*)(&Ps[rs_ * 16 + lr][hf_ * 32 + lq * 8]);    \
    for (int df_ = 0; df_ < 4; ++df_) {                                             \
      o[0][df_] = MFMA16(pa_[0][0], vb[df_][0], o[0][df_]);                         \
      o[0][df_] = MFMA16(pa_[0][1], vb[df_][1], o[0][df_]);                         \
      o[1][df_] = MFMA16(pa_[1][0], vb[df_][0], o[1][df_]);                         \
      o[1][df_] = MFMA16(pa_[1][1], vb[df_][1], o[1][df_]);                         \
    }                                                                               \
  }

__global__ __launch_bounds__(64, 2) void attn_fb(const unsigned short* __restrict__ Qp,
                                                 const unsigned short* __restrict__ Kp,
                                                 const unsigned short* __restrict__ Vt,
                                                 const int* __restrict__ lens,
                                                 unsigned short* __restrict__ attno) {
  __shared__ unsigned short Ps[32][72];
  const int i = blockIdx.x;
  const int xcd = i & 7, bh8 = (i >> 3) & 7, slot = i >> 6;  // slot 0..63
  const int qt = 15 - (slot >> 2), wv = slot & 3;            // heavy first
  const int bh = bh8 * 8 + xcd;
  const int b = bh >> 4, h = bh & 15;
  const int rowbase = (qt << 7) + (wv << 5);
  const int len = lens[b];
  if (rowbase >= len) return;  // rows handled by padfix

  const int tid = threadIdx.x, lr = tid & 15, lq = tid >> 4;

  const unsigned short* Kbase = Kp + (size_t)(b * CL) * CD + h * 64;
  const unsigned short* Vbase = Vt + ((size_t)(bh * 64) << 11);
  const unsigned short* Qbase = Qp + (size_t)(b * CL + rowbase) * CD + h * 64;

  bf16x8 qa[2][2];
#pragma unroll
  for (int rs = 0; rs < 2; ++rs)
#pragma unroll
    for (int hf = 0; hf < 2; ++hf)
      qa[rs][hf] = *(const bf16x8*)(Qbase + (size_t)(rs * 16 + lr) * CD + hf * 32 + lq * 8);

  f32x4 o[2][4] = {};
  float lsum[2][4] = {};
  const int kdiag = rowbase >> 6;

  bf16x8 kfA[4][2], kfB[4][2], vb[4][2];
  LOADK(0, kfA);

  int kt = 0;
  while (true) {
    TILE_FB(kt, kfA, kfB);
    if (kt == kdiag) break;
    ++kt;
    TILE_FB(kt, kfB, kfA);
    if (kt == kdiag) break;
    ++kt;
  }

  float inv[2][4];
#pragma unroll
  for (int rs = 0; rs < 2; ++rs)
#pragma unroll
    for (int j = 0; j < 4; ++j) {
      float t = lsum[rs][j];
      t += __shfl_xor(t, 1);
      t += __shfl_xor(t, 2);
      t += __shfl_xor(t, 4);
      t += __shfl_xor(t, 8);
      inv[rs][j] = __builtin_amdgcn_rcpf(t);
    }

#pragma unroll
  for (int rs = 0; rs < 2; ++rs)
#pragma unroll
    for (int df = 0; df < 4; ++df)
#pragma unroll
      for (int j = 0; j < 4; ++j)
        attno[(size_t)(b * CL + rowbase + rs * 16 + lq * 4 + j) * CD + h * 64 + df * 16 +
              lr] = f2bf(o[rs][df][j] * inv[rs][j]);
}

// ---------------- padded-query fixup: uniform attention = mean of V rows -------

__global__ __launch_bounds__(256) void padfix_kernel(const int* __restrict__ lens,
                                                     const float* __restrict__ meanv,
                                                     unsigned short* __restrict__ attno) {
  const int q = blockIdx.x & (CL - 1);
  const int b = blockIdx.x >> 11;
  if (q < lens[b]) return;
#pragma unroll
  for (int i = 0; i < 4; ++i) {
    const int col = threadIdx.x + i * 256;
    attno[(size_t)(b * CL + q) * CD + col] = f2bf(meanv[b * CD + col]);
  }
}

// ---------------- launch ----------------

extern "C" void kernel_launch(void* const* d_in, const int* in_sizes, int n_in,
                              void* d_out, int out_size, void* d_ws, size_t ws_size,
                              hipStream_t stream) {
  const float* q  = (const float*)d_in[0];
  const float* k  = (const float*)d_in[1];
  const float* v  = (const float*)d_in[2];
  const int*   am = (const int*)d_in[3];
  const float* Wq = (const float*)d_in[4];
  const float* bq = (const float*)d_in[5];
  const float* Wk = (const float*)d_in[6];
  const float* bk = (const float*)d_in[7];
  const float* Wv = (const float*)d_in[8];
  const float* bv = (const float*)d_in[9];
  const float* Wc = (const float*)d_in[10];
  const float* bc = (const float*)d_in[11];
  float* out = (float*)d_out;

  unsigned short* Wqb = (unsigned short*)d_ws;   // Wqb|Wkb|Wvb|Wcb contiguous
  unsigned short* Wkb = Wqb + (1 << 20);
  unsigned short* Wvb = Wkb + (1 << 20);
  unsigned short* Wcb = Wvb + (1 << 20);
  unsigned short* Xq  = Wcb + (1 << 20);          // also attn-out (X aliases Xq)
  unsigned short* Xk  = Xq + (size_t)CM * CD;
  unsigned short* Xv  = Xk + (size_t)CM * CD;
  unsigned short* Qp  = Xv + (size_t)CM * CD;
  unsigned short* Kp  = Qp + (size_t)CM * CD;
  unsigned short* Vt  = Kp + (size_t)CM * CD;     // [B,H,DH,L]
  float* meanv = (float*)(Vt + (size_t)CM * CD);  // [B, D]
  int* lens = (int*)(meanv + CB * CD);
  unsigned short* X = Xq;

  lens_kernel<<<CB, 256, 0, stream>>>(am, lens);
  cvt_all<<<14336, 256, 0, stream>>>(q, k, v, Wq, Wk, Wv, Wc, Xq, Xk, Xv,
                                     Wqb, Wkb, Wvb, Wcb);

  const float QSCALE = 0.125f * 1.44269504f;  // folded 1/sqrt(DH) * log2(e)

  gemm_qkv<<<1536, 512, 0, stream>>>(Xq, Xk, Xv, Wqb, bq, bk, bv, Qp, Kp, Vt, QSCALE);

  meanv_kernel<<<1024, 256, 0, stream>>>(Vt, meanv);

  // spill-guard (R16 pattern): use the LDS-ring block kernel only if spill-free.
  hipFuncAttributes fa{};
  bool blk_ok = false;
  if (hipFuncGetAttributes(&fa, (const void*)attn_blk) == hipSuccess)
    blk_ok = (fa.localSizeBytes == 0);
  if (blk_ok)
    attn_blk<<<1024, 256, 0, stream>>>(Qp, Kp, Vt, lens, X);
  else
    attn_fb<<<4096, 64, 0, stream>>>(Qp, Kp, Vt, lens, X);

  padfix_kernel<<<CB * CL, 256, 0, stream>>>(lens, meanv, X);

  gemm_out<<<512, 512, 0, stream>>>(X, Wcb, bc, out);
}

// Round 23
// 186.901 us; speedup vs baseline: 1.1017x; 1.0242x over previous
//
#include <hip/hip_runtime.h>
#include <stdint.h>

typedef __bf16 bf16x8 __attribute__((ext_vector_type(8)));
typedef float f32x4 __attribute__((ext_vector_type(4)));
typedef unsigned short ushort8 __attribute__((ext_vector_type(8)));
typedef unsigned short ushort4v __attribute__((ext_vector_type(4)));

constexpr int CB = 4;
constexpr int CL = 2048;
constexpr int CD = 1024;
constexpr int CH = 16;
constexpr int CDH = 64;
constexpr int CM = CB * CL;  // 8192

__device__ __forceinline__ unsigned short f2bf(float f) {
  union { float f; unsigned u; } x; x.f = f;
  unsigned r = x.u + 0x7fffu + ((x.u >> 16) & 1u);
  return (unsigned short)(r >> 16);
}
__device__ __forceinline__ float bf2f(unsigned short b) {
  union { unsigned u; float f; } x; x.u = ((unsigned)b) << 16;
  return x.f;
}

__device__ __forceinline__ void gld_lds16(const void* g, void* l) {
  __builtin_amdgcn_global_load_lds((const __attribute__((address_space(1))) void*)g,
                                   (__attribute__((address_space(3))) void*)l, 16, 0, 0);
}

#define MFMA16(a, b, c) __builtin_amdgcn_mfma_f32_16x16x32_bf16((a), (b), (c), 0, 0, 0)

// ---------------- fp32 -> bf16: weights + q/k/v in ONE launch ------------------

__global__ __launch_bounds__(256) void cvt_all(const float* __restrict__ q,
                                               const float* __restrict__ k,
                                               const float* __restrict__ v,
                                               const float* __restrict__ Wq,
                                               const float* __restrict__ Wk,
                                               const float* __restrict__ Wv,
                                               const float* __restrict__ Wc,
                                               unsigned short* __restrict__ oq,
                                               unsigned short* __restrict__ ok,
                                               unsigned short* __restrict__ ov,
                                               unsigned short* __restrict__ oWq,
                                               unsigned short* __restrict__ oWk,
                                               unsigned short* __restrict__ oWv,
                                               unsigned short* __restrict__ oWc) {
  int bi = blockIdx.x;
  const float* s;
  unsigned short* d;
  int i;
  if (bi < 2048) {
    const int w = bi >> 9;
    i = (bi & 511) * 256 + threadIdx.x;
    s = w == 0 ? Wq : w == 1 ? Wk : w == 2 ? Wv : Wc;
    d = w == 0 ? oWq : w == 1 ? oWk : w == 2 ? oWv : oWc;
  } else {
    bi -= 2048;
    const int w = bi >> 12;
    i = (bi & 4095) * 256 + threadIdx.x;
    s = w == 0 ? q : w == 1 ? k : v;
    d = w == 0 ? oq : w == 1 ? ok : ov;
  }
  const float4* sp = (const float4*)s;
  float4 a = sp[2 * i], b = sp[2 * i + 1];
  ushort8 o;
  o[0] = f2bf(a.x); o[1] = f2bf(a.y); o[2] = f2bf(a.z); o[3] = f2bf(a.w);
  o[4] = f2bf(b.x); o[5] = f2bf(b.y); o[6] = f2bf(b.z); o[7] = f2bf(b.w);
  ((ushort8*)d)[i] = o;
}

// ---------------- lengths from prefix mask ----------------

__global__ __launch_bounds__(256) void lens_kernel(const int* __restrict__ mask,
                                                   int* __restrict__ lens) {
  __shared__ int part[4];
  const int b = blockIdx.x;
  int cnt = 0;
  for (int i = threadIdx.x; i < CL; i += 256) cnt += (mask[b * CL + i] != 0) ? 1 : 0;
#pragma unroll
  for (int off = 32; off; off >>= 1) cnt += __shfl_down(cnt, off);
  if ((threadIdx.x & 63) == 0) part[threadIdx.x >> 6] = cnt;
  __syncthreads();
  if (threadIdx.x == 0) lens[b] = part[0] + part[1] + part[2] + part[3];
}

// ---------------- GEMM pipeline: R22 winner (8-wave 3-ring + T2 swizzle) -------

#define GEMM_WAIT2(kt, nkt)                                             \
  {                                                                     \
    if ((kt) + 1 < (nkt))                                               \
      asm volatile("s_waitcnt vmcnt(2)" ::: "memory");                  \
    else                                                                \
      asm volatile("s_waitcnt vmcnt(0)" ::: "memory");                  \
    __builtin_amdgcn_s_barrier();                                       \
    asm volatile("" ::: "memory");                                      \
  }

// ---------------- fused QKV GEMM (bf16 A via global_load_lds), N = 3072 --------

__global__ __launch_bounds__(512) void gemm_qkv(const unsigned short* __restrict__ Xq,
                                                const unsigned short* __restrict__ Xk,
                                                const unsigned short* __restrict__ Xv,
                                                const unsigned short* __restrict__ Wb,
                                                const float* __restrict__ bq,
                                                const float* __restrict__ bk,
                                                const float* __restrict__ bv,
                                                unsigned short* __restrict__ Qp,
                                                unsigned short* __restrict__ Kp,
                                                unsigned short* __restrict__ Vt,
                                                float qscale) {
  __shared__ unsigned short Asm[3][128 * 32];
  __shared__ unsigned short Bsm[3][128 * 32];
  const int tid = threadIdx.x;
  const int w = tid >> 6, ln = tid & 63, lr = ln & 15, lq = ln >> 4;
  const int nbx = 24;  // 3072/128
  const int cpx = (int)gridDim.x >> 3;
  const int bid = ((int)blockIdx.x & 7) * cpx + ((int)blockIdx.x >> 3);
  const int bm = (bid / nbx) << 7;
  const int bnG = (bid % nbx) << 7;
  const int which = bnG >> 10, bn = bnG & 1023;
  const unsigned short* A = which == 0 ? Xq : which == 1 ? Xk : Xv;
  const unsigned short* Bw = Wb + ((size_t)which << 20);
  const float* bias = which == 0 ? bq : which == 1 ? bk : bv;
  const float alpha = which == 0 ? qscale : 1.0f;
  const int wr = (w >> 1) << 5, wc = (w & 1) << 6;   // wave tile 32x64

  f32x4 acc[2][4] = {};
  const int arow = tid >> 2;
  const int akc = (((tid & 3) ^ ((arow >> 1) & 3)) << 3);  // pre-swizzled source chunk

  auto stage = [&](int buf, int k0) {
    gld_lds16(A + (size_t)(bm + arow) * CD + k0 + akc, (void*)(Asm[buf] + w * 512));
    gld_lds16(Bw + (size_t)(bn + arow) * CD + k0 + akc, (void*)(Bsm[buf] + w * 512));
  };

  stage(0, 0);
  stage(1, 32);

  const int nkt = CD >> 5;  // 32
  int cur = 0;
  for (int kt = 0; kt < nkt; ++kt) {
    GEMM_WAIT2(kt, nkt);
    if (kt + 2 < nkt) {
      int nb = cur + 2;
      if (nb >= 3) nb -= 3;
      stage(nb, (kt + 2) << 5);
    }
    bf16x8 af[2], bfr[4];
#pragma unroll
    for (int f = 0; f < 2; ++f) {
      const int R = wr + f * 16 + lr;
      af[f] = *(const bf16x8*)(Asm[cur] + (R * 32 + ((lq ^ ((R >> 1) & 3)) << 3)));
    }
#pragma unroll
    for (int f = 0; f < 4; ++f) {
      const int R = wc + f * 16 + lr;
      bfr[f] = *(const bf16x8*)(Bsm[cur] + (R * 32 + ((lq ^ ((R >> 1) & 3)) << 3)));
    }
#pragma unroll
    for (int fm = 0; fm < 2; ++fm)
#pragma unroll
      for (int fn = 0; fn < 4; ++fn)
        acc[fm][fn] = MFMA16(af[fm], bfr[fn], acc[fm][fn]);
    if (++cur == 3) cur = 0;
  }

#pragma unroll
  for (int fm = 0; fm < 2; ++fm) {
    const int row0 = bm + wr + fm * 16 + lq * 4;
#pragma unroll
    for (int fn = 0; fn < 4; ++fn) {
      const int col = bn + wc + fn * 16 + lr;
      const float bb = bias[col];
      if (which == 2) {
        const int b = row0 >> 11, lrow = row0 & (CL - 1);
        const int hh = col >> 6, dh = col & 63;
        ushort4v pk;
#pragma unroll
        for (int j = 0; j < 4; ++j) pk[j] = f2bf(acc[fm][fn][j] + bb);
        *(ushort4v*)(Vt + (((size_t)((b * CH + hh) * CDH + dh)) << 11) + lrow) = pk;
      } else {
        unsigned short* outp = which == 0 ? Qp : Kp;
#pragma unroll
        for (int j = 0; j < 4; ++j)
          outp[(size_t)(row0 + j) * CD + col] = f2bf((acc[fm][fn][j] + bb) * alpha);
      }
    }
  }
}

// ---------------- final GEMM: out = X * Wc^T + bc (f32 out) --------------------

__global__ __launch_bounds__(512) void gemm_out(const unsigned short* __restrict__ A,
                                                const unsigned short* __restrict__ Bw,
                                                const float* __restrict__ bias,
                                                float* __restrict__ Cout) {
  __shared__ unsigned short Asm[3][128 * 32];
  __shared__ unsigned short Bsm[3][128 * 32];
  const int tid = threadIdx.x;
  const int w = tid >> 6, ln = tid & 63, lr = ln & 15, lq = ln >> 4;
  const int nbx = CD >> 7;
  const int cpx = (int)gridDim.x >> 3;
  const int bid = ((int)blockIdx.x & 7) * cpx + ((int)blockIdx.x >> 3);
  const int bm = (bid / nbx) << 7;
  const int bn = (bid % nbx) << 7;
  const int wr = (w >> 1) << 5, wc = (w & 1) << 6;

  f32x4 acc[2][4] = {};
  const int arow = tid >> 2;
  const int akc = (((tid & 3) ^ ((arow >> 1) & 3)) << 3);

  auto stage = [&](int buf, int k0) {
    gld_lds16(A + (size_t)(bm + arow) * CD + k0 + akc, (void*)(Asm[buf] + w * 512));
    gld_lds16(Bw + (size_t)(bn + arow) * CD + k0 + akc, (void*)(Bsm[buf] + w * 512));
  };

  stage(0, 0);
  stage(1, 32);

  const int nkt = CD >> 5;  // 32
  int cur = 0;
  for (int kt = 0; kt < nkt; ++kt) {
    GEMM_WAIT2(kt, nkt);
    if (kt + 2 < nkt) {
      int nb = cur + 2;
      if (nb >= 3) nb -= 3;
      stage(nb, (kt + 2) << 5);
    }
    bf16x8 af[2], bfr[4];
#pragma unroll
    for (int f = 0; f < 2; ++f) {
      const int R = wr + f * 16 + lr;
      af[f] = *(const bf16x8*)(Asm[cur] + (R * 32 + ((lq ^ ((R >> 1) & 3)) << 3)));
    }
#pragma unroll
    for (int f = 0; f < 4; ++f) {
      const int R = wc + f * 16 + lr;
      bfr[f] = *(const bf16x8*)(Bsm[cur] + (R * 32 + ((lq ^ ((R >> 1) & 3)) << 3)));
    }
#pragma unroll
    for (int fm = 0; fm < 2; ++fm)
#pragma unroll
      for (int fn = 0; fn < 4; ++fn)
        acc[fm][fn] = MFMA16(af[fm], bfr[fn], acc[fm][fn]);
    if (++cur == 3) cur = 0;
  }

#pragma unroll
  for (int fm = 0; fm < 2; ++fm) {
    const int row0 = bm + wr + fm * 16 + lq * 4;
#pragma unroll
    for (int fn = 0; fn < 4; ++fn) {
      const int col = bn + wc + fn * 16 + lr;
      const float bb = bias[col];
#pragma unroll
      for (int j = 0; j < 4; ++j)
        Cout[(size_t)(row0 + j) * CD + col] = acc[fm][fn][j] + bb;
    }
  }
}

// ---------------- mean over L of each Vt row ----------------

__global__ __launch_bounds__(256) void meanv_kernel(const unsigned short* __restrict__ Vt,
                                                    float* __restrict__ meanv) {
  const int row = blockIdx.x * 4 + (threadIdx.x >> 6);
  const int ln = threadIdx.x & 63;
  const ushort8* p = (const ushort8*)(Vt + (size_t)row * CL);
  float s = 0.f;
#pragma unroll
  for (int it = 0; it < 4; ++it) {
    ushort8 v = p[it * 64 + ln];
#pragma unroll
    for (int j = 0; j < 8; ++j) s += bf2f(v[j]);
  }
#pragma unroll
  for (int off = 32; off; off >>= 1) s += __shfl_down(s, off);
  if (ln == 0) meanv[row] = s * (1.f / (float)CL);
}

// ---------------- attn_blk: 4-wave block, LDS K/V ring + T2 involution swizzle -
// [64][64] bf16 tiles have 128B rows: unswizzled, each fragment read is a
// 16-way bank conflict (16 lanes, same chunk, different rows). Fix per rule
// #21: LDS dest stays linear (gld_lds requirement); the staging lane pre-
// swizzles its GLOBAL source chunk (c_src = (ln&7) ^ ((ln>>3)&7), since
// row&7 == (ln>>3)&7 for both p-halves), so LDS[row][c'] = global[row][c'^
// (row&7)]; every fragment read fetches chunk c ^ (R&7). lr=0..7 now cover
// all 8 chunks (32 banks); lr vs lr+8 alias 2-way (free).

__global__ __launch_bounds__(256, 2) void attn_blk(const unsigned short* __restrict__ Qp,
                                                   const unsigned short* __restrict__ Kp,
                                                   const unsigned short* __restrict__ Vt,
                                                   const int* __restrict__ lens,
                                                   unsigned short* __restrict__ attno) {
  __shared__ unsigned short Ks[3][64 * 64];
  __shared__ unsigned short Vs[3][64 * 64];
  __shared__ unsigned short Ps[4][32][72];
  const int i = blockIdx.x;
  const int xcd = i & 7, bh8 = (i >> 3) & 7, slot = i >> 6;  // slot 0..15
  const int qt = 15 - slot;                                  // heavy first
  const int bh = bh8 * 8 + xcd;
  const int b = bh >> 4, h = bh & 15;
  const int qbase = qt << 7;
  const int len = lens[b];
  if (qbase >= len) return;  // whole block padded; padfix covers

  const int tid = threadIdx.x, w = tid >> 6, ln = tid & 63, lr = ln & 15, lq = ln >> 4;
  const int rowbase = qbase + (w << 5);     // this wave's 32 q-rows
  const int kdw = rowbase >> 6;             // wave's diagonal tile
  const int ntiles = 2 * qt + 2;            // block iterates tiles 0..2qt+1

  const unsigned short* Kbase = Kp + (size_t)(b * CL) * CD + h * 64;
  const unsigned short* Vbase = Vt + ((size_t)(bh * 64) << 11);
  const unsigned short* Qbase = Qp + (size_t)(b * CL + rowbase) * CD + h * 64;

  const int srow = (w << 4) + (ln >> 3);
  const int scolS = (((ln & 7) ^ ((ln >> 3) & 7)) << 3);  // pre-swizzled source chunk
  auto stage = [&](int buf, int kt) {
    const int kb = kt << 6;
#pragma unroll
    for (int p = 0; p < 2; ++p) {
      gld_lds16(Kbase + (size_t)(kb + srow + p * 8) * CD + scolS,
                (void*)(Ks[buf] + (w << 10) + (p << 9)));
      gld_lds16(Vbase + (size_t)(srow + p * 8) * CL + kb + scolS,
                (void*)(Vs[buf] + (w << 10) + (p << 9)));
    }
  };

  bf16x8 qa[2][2];
#pragma unroll
  for (int rs = 0; rs < 2; ++rs)
#pragma unroll
    for (int hf = 0; hf < 2; ++hf)
      qa[rs][hf] = *(const bf16x8*)(Qbase + (size_t)(rs * 16 + lr) * CD + hf * 32 + lq * 8);
  __builtin_amdgcn_sched_barrier(0);
  stage(0, 0);
  __builtin_amdgcn_sched_barrier(0);
  stage(1, 1);
  __builtin_amdgcn_sched_barrier(0);

  f32x4 o[2][4] = {};
  float lsum[2][4] = {};

  int cur = 0;
  for (int kt = 0; kt < ntiles; ++kt) {
    if (kt + 1 < ntiles)
      asm volatile("s_waitcnt vmcnt(4)" ::: "memory");
    else
      asm volatile("s_waitcnt vmcnt(0)" ::: "memory");
    __builtin_amdgcn_s_barrier();
    asm volatile("" ::: "memory");
    if (kt + 2 < ntiles) {
      int nb = cur + 2;
      if (nb >= 3) nb -= 3;
      stage(nb, kt + 2);
    }

    if (kt <= kdw) {
      const bool dm = (kt == kdw);
      const int kb = kt << 6;
      const unsigned short* Kc = Ks[cur];
      const unsigned short* Vc = Vs[cur];

      bf16x8 kf[4][2];
#pragma unroll
      for (int cf = 0; cf < 4; ++cf)
#pragma unroll
        for (int hf = 0; hf < 2; ++hf)
          kf[cf][hf] = *(const bf16x8*)(Kc + (cf * 16 + lr) * 64 +
                                        ((((hf << 2) + lq) ^ (lr & 7)) << 3));

#pragma unroll
      for (int rs = 0; rs < 2; ++rs) {
        f32x4 s_[4];
#pragma unroll
        for (int cf = 0; cf < 4; ++cf) {
          f32x4 z = {};
          z = MFMA16(qa[rs][0], kf[cf][0], z);
          z = MFMA16(qa[rs][1], kf[cf][1], z);
          s_[cf] = z;
        }
#pragma unroll
        for (int cf = 0; cf < 4; ++cf) {
#pragma unroll
          for (int j = 0; j < 4; ++j) {
            float p = __builtin_amdgcn_exp2f(s_[cf][j]);
            if (dm) {
              const int key = kb + cf * 16 + lr;
              const int row = rowbase + rs * 16 + lq * 4 + j;
              p = (key > row) ? 0.f : p;
            }
            lsum[rs][j] += p;
            Ps[w][rs * 16 + lq * 4 + j][cf * 16 + lr] =
                (unsigned short)(__builtin_bit_cast(unsigned int, p) >> 16);
          }
        }
      }

      bf16x8 pa[2][2];
#pragma unroll
      for (int rs = 0; rs < 2; ++rs)
#pragma unroll
        for (int hf = 0; hf < 2; ++hf)
          pa[rs][hf] = *(const bf16x8*)(&Ps[w][rs * 16 + lr][hf * 32 + lq * 8]);

#pragma unroll
      for (int df = 0; df < 4; ++df) {
        const int vr = (df * 16 + lr) * 64;
        const bf16x8 vb0 = *(const bf16x8*)(Vc + vr + ((lq ^ (lr & 7)) << 3));
        const bf16x8 vb1 = *(const bf16x8*)(Vc + vr + (((4 + lq) ^ (lr & 7)) << 3));
        o[0][df] = MFMA16(pa[0][0], vb0, o[0][df]);
        o[0][df] = MFMA16(pa[0][1], vb1, o[0][df]);
        o[1][df] = MFMA16(pa[1][0], vb0, o[1][df]);
        o[1][df] = MFMA16(pa[1][1], vb1, o[1][df]);
      }
    }
    if (++cur == 3) cur = 0;
  }

  float inv[2][4];
#pragma unroll
  for (int rs = 0; rs < 2; ++rs)
#pragma unroll
    for (int j = 0; j < 4; ++j) {
      float t = lsum[rs][j];
      t += __shfl_xor(t, 1);
      t += __shfl_xor(t, 2);
      t += __shfl_xor(t, 4);
      t += __shfl_xor(t, 8);
      inv[rs][j] = __builtin_amdgcn_rcpf(t);
    }

#pragma unroll
  for (int rs = 0; rs < 2; ++rs)
#pragma unroll
    for (int df = 0; df < 4; ++df)
#pragma unroll
      for (int j = 0; j < 4; ++j)
        attno[(size_t)(b * CL + rowbase + rs * 16 + lq * 4 + j) * CD + h * 64 + df * 16 +
              lr] = f2bf(o[rs][df][j] * inv[rs][j]);
}

// ---------------- attn_fb: R10/R16 32-row single-deep body (stable fallback) ---

#define LOADK(kt, dst)                                                              \
  {                                                                                 \
    const int kb_ = (kt) << 6;                                                      \
    for (int cf_ = 0; cf_ < 4; ++cf_)                                               \
      for (int hf_ = 0; hf_ < 2; ++hf_)                                             \
        dst[cf_][hf_] = *(const bf16x8*)(Kbase + (size_t)(kb_ + cf_ * 16 + lr) * CD + \
                                         hf_ * 32 + lq * 8);                        \
  }

#define VLOAD_FB(kt, dst)                                                           \
  {                                                                                 \
    const int kb_ = (kt) << 6;                                                      \
    for (int df_ = 0; df_ < 4; ++df_)                                               \
      for (int hf_ = 0; hf_ < 2; ++hf_)                                             \
        dst[df_][hf_] = *(const bf16x8*)(Vbase + (((size_t)(df_ * 16 + lr)) << 11) +  \
                                         kb_ + hf_ * 32 + lq * 8);                  \
  }

#define TILE_FB(kt, KF, KN)                                                         \
  {                                                                                 \
    const bool dm_ = (kt) == kdiag;                                                 \
    const int kb_ = (kt) << 6;                                                      \
    f32x4 s_[2][4];                                                                 \
    for (int rs_ = 0; rs_ < 2; ++rs_)                                               \
      for (int cf_ = 0; cf_ < 4; ++cf_) {                                           \
        f32x4 z_ = {};                                                              \
        z_ = MFMA16(qa[rs_][0], KF[cf_][0], z_);                                    \
        z_ = MFMA16(qa[rs_][1], KF[cf_][1], z_);                                    \
        s_[rs_][cf_] = z_;                                                          \
      }                                                                             \
    VLOAD_FB(kt, vb);                                                               \
    if ((kt) < kdiag) LOADK((kt) + 1, KN);                                          \
    __builtin_amdgcn_sched_barrier(0);                                              \
    for (int rs_ = 0; rs_ < 2; ++rs_)                                               \
      for (int cf_ = 0; cf_ < 4; ++cf_)                                             \
        for (int j_ = 0; j_ < 4; ++j_) {                                            \
          float p_ = __builtin_amdgcn_exp2f(s_[rs_][cf_][j_]);                      \
          if (dm_) {                                                                \
            const int key_ = kb_ + cf_ * 16 + lr;                                   \
            const int row_ = rowbase + rs_ * 16 + lq * 4 + j_;                      \
            p_ = (key_ > row_) ? 0.f : p_;                                          \
          }                                                                         \
          lsum[rs_][j_] += p_;                                                      \
          Ps[rs_ * 16 + lq * 4 + j_][cf_ * 16 + lr] =                               \
              (unsigned short)(__builtin_bit_cast(unsigned int, p_) >> 16);         \
        }                                                                           \
    bf16x8 pa_[2][2];                                                               \
    for (int rs_ = 0; rs_ < 2; ++rs_)                                               \
      for (int hf_ = 0; hf_ < 2; ++hf_)                                             \
        pa_[rs_][hf_] = *(const bf16x8*)(&Ps[rs_ * 16 + lr][hf_ * 32 + lq * 8]);    \
    for (int df_ = 0; df_ < 4; ++df_) {                                             \
      o[0][df_] = MFMA16(pa_[0][0], vb[df_][0], o[0][df_]);                         \
      o[0][df_] = MFMA16(pa_[0][1], vb[df_][1], o[0][df_]);                         \
      o[1][df_] = MFMA16(pa_[1][0], vb[df_][0], o[1][df_]);                         \
      o[1][df_] = MFMA16(pa_[1][1], vb[df_][1], o[1][df_]);                         \
    }                                                                               \
  }

__global__ __launch_bounds__(64, 2) void attn_fb(const unsigned short* __restrict__ Qp,
                                                 const unsigned short* __restrict__ Kp,
                                                 const unsigned short* __restrict__ Vt,
                                                 const int* __restrict__ lens,
                                                 unsigned short* __restrict__ attno) {
  __shared__ unsigned short Ps[32][72];
  const int i = blockIdx.x;
  const int xcd = i & 7, bh8 = (i >> 3) & 7, slot = i >> 6;  // slot 0..63
  const int qt = 15 - (slot >> 2), wv = slot & 3;            // heavy first
  const int bh = bh8 * 8 + xcd;
  const int b = bh >> 4, h = bh & 15;
  const int rowbase = (qt << 7) + (wv << 5);
  const int len = lens[b];
  if (rowbase >= len) return;  // rows handled by padfix

  const int tid = threadIdx.x, lr = tid & 15, lq = tid >> 4;

  const unsigned short* Kbase = Kp + (size_t)(b * CL) * CD + h * 64;
  const unsigned short* Vbase = Vt + ((size_t)(bh * 64) << 11);
  const unsigned short* Qbase = Qp + (size_t)(b * CL + rowbase) * CD + h * 64;

  bf16x8 qa[2][2];
#pragma unroll
  for (int rs = 0; rs < 2; ++rs)
#pragma unroll
    for (int hf = 0; hf < 2; ++hf)
      qa[rs][hf] = *(const bf16x8*)(Qbase + (size_t)(rs * 16 + lr) * CD + hf * 32 + lq * 8);

  f32x4 o[2][4] = {};
  float lsum[2][4] = {};
  const int kdiag = rowbase >> 6;

  bf16x8 kfA[4][2], kfB[4][2], vb[4][2];
  LOADK(0, kfA);

  int kt = 0;
  while (true) {
    TILE_FB(kt, kfA, kfB);
    if (kt == kdiag) break;
    ++kt;
    TILE_FB(kt, kfB, kfA);
    if (kt == kdiag) break;
    ++kt;
  }

  float inv[2][4];
#pragma unroll
  for (int rs = 0; rs < 2; ++rs)
#pragma unroll
    for (int j = 0; j < 4; ++j) {
      float t = lsum[rs][j];
      t += __shfl_xor(t, 1);
      t += __shfl_xor(t, 2);
      t += __shfl_xor(t, 4);
      t += __shfl_xor(t, 8);
      inv[rs][j] = __builtin_amdgcn_rcpf(t);
    }

#pragma unroll
  for (int rs = 0; rs < 2; ++rs)
#pragma unroll
    for (int df = 0; df < 4; ++df)
#pragma unroll
      for (int j = 0; j < 4; ++j)
        attno[(size_t)(b * CL + rowbase + rs * 16 + lq * 4 + j) * CD + h * 64 + df * 16 +
              lr] = f2bf(o[rs][df][j] * inv[rs][j]);
}

// ---------------- padded-query fixup: uniform attention = mean of V rows -------

__global__ __launch_bounds__(256) void padfix_kernel(const int* __restrict__ lens,
                                                     const float* __restrict__ meanv,
                                                     unsigned short* __restrict__ attno) {
  const int q = blockIdx.x & (CL - 1);
  const int b = blockIdx.x >> 11;
  if (q < lens[b]) return;
#pragma unroll
  for (int i = 0; i < 4; ++i) {
    const int col = threadIdx.x + i * 256;
    attno[(size_t)(b * CL + q) * CD + col] = f2bf(meanv[b * CD + col]);
  }
}

// ---------------- launch ----------------

extern "C" void kernel_launch(void* const* d_in, const int* in_sizes, int n_in,
                              void* d_out, int out_size, void* d_ws, size_t ws_size,
                              hipStream_t stream) {
  const float* q  = (const float*)d_in[0];
  const float* k  = (const float*)d_in[1];
  const float* v  = (const float*)d_in[2];
  const int*   am = (const int*)d_in[3];
  const float* Wq = (const float*)d_in[4];
  const float* bq = (const float*)d_in[5];
  const float* Wk = (const float*)d_in[6];
  const float* bk = (const float*)d_in[7];
  const float* Wv = (const float*)d_in[8];
  const float* bv = (const float*)d_in[9];
  const float* Wc = (const float*)d_in[10];
  const float* bc = (const float*)d_in[11];
  float* out = (float*)d_out;

  unsigned short* Wqb = (unsigned short*)d_ws;   // Wqb|Wkb|Wvb|Wcb contiguous
  unsigned short* Wkb = Wqb + (1 << 20);
  unsigned short* Wvb = Wkb + (1 << 20);
  unsigned short* Wcb = Wvb + (1 << 20);
  unsigned short* Xq  = Wcb + (1 << 20);          // also attn-out (X aliases Xq)
  unsigned short* Xk  = Xq + (size_t)CM * CD;
  unsigned short* Xv  = Xk + (size_t)CM * CD;
  unsigned short* Qp  = Xv + (size_t)CM * CD;
  unsigned short* Kp  = Qp + (size_t)CM * CD;
  unsigned short* Vt  = Kp + (size_t)CM * CD;     // [B,H,DH,L]
  float* meanv = (float*)(Vt + (size_t)CM * CD);  // [B, D]
  int* lens = (int*)(meanv + CB * CD);
  unsigned short* X = Xq;

  lens_kernel<<<CB, 256, 0, stream>>>(am, lens);
  cvt_all<<<14336, 256, 0, stream>>>(q, k, v, Wq, Wk, Wv, Wc, Xq, Xk, Xv,
                                     Wqb, Wkb, Wvb, Wcb);

  const float QSCALE = 0.125f * 1.44269504f;  // folded 1/sqrt(DH) * log2(e)

  gemm_qkv<<<1536, 512, 0, stream>>>(Xq, Xk, Xv, Wqb, bq, bk, bv, Qp, Kp, Vt, QSCALE);

  meanv_kernel<<<1024, 256, 0, stream>>>(Vt, meanv);

  // spill-guard (R16 pattern): use the LDS-ring block kernel only if spill-free.
  hipFuncAttributes fa{};
  bool blk_ok = false;
  if (hipFuncGetAttributes(&fa, (const void*)attn_blk) == hipSuccess)
    blk_ok = (fa.localSizeBytes == 0);
  if (blk_ok)
    attn_blk<<<1024, 256, 0, stream>>>(Qp, Kp, Vt, lens, X);
  else
    attn_fb<<<4096, 64, 0, stream>>>(Qp, Kp, Vt, lens, X);

  padfix_kernel<<<CB * CL, 256, 0, stream>>>(lens, meanv, X);

  gemm_out<<<512, 512, 0, stream>>>(X, Wcb, bc, out);
}